// Round 8
// baseline (266.930 us; speedup 1.0000x reference)
//
#include <hip/hip_runtime.h>

#define LSEQ 256
#define DMODEL 512
#define NHEAD 8
#define DKH 64
#define BATCH 4
#define NBLK 256

#define TWO_LOG2E 2.885390081777927f

using short8 = __attribute__((ext_vector_type(8))) short;
using f32x4  = __attribute__((ext_vector_type(4))) float;

// split fp32 -> truncated bf16 hi + bf16(lo remainder)
__device__ __forceinline__ void split4(const float* f, ushort4& h, ushort4& l) {
  unsigned short hh[4], ll[4];
#pragma unroll
  for (int j = 0; j < 4; ++j) {
    unsigned int u = __float_as_uint(f[j]);
    hh[j] = (unsigned short)(u >> 16);
    float hf = __uint_as_float(u & 0xFFFF0000u);
    ll[j] = (unsigned short)(__float_as_uint(f[j] - hf) >> 16);
  }
  h = make_ushort4(hh[0], hh[1], hh[2], hh[3]);
  l = make_ushort4(ll[0], ll[1], ll[2], ll[3]);
}

__device__ __forceinline__ void split8(float4 f0, float4 f1, short8& h, short8& l) {
  float f[8] = {f0.x, f0.y, f0.z, f0.w, f1.x, f1.y, f1.z, f1.w};
#pragma unroll
  for (int j = 0; j < 8; ++j) {
    unsigned int u = __float_as_uint(f[j]);
    h[j] = (short)(u >> 16);
    float hf = __uint_as_float(u & 0xFFFF0000u);
    l[j] = (short)(__float_as_uint(f[j] - hf) >> 16);
  }
}

__global__ void init_kernel(unsigned* bar) { bar[0] = 0u; bar[1] = 0u; }

// device-scope sense barrier: all NBLK blocks must be co-resident (1/CU by LDS)
__device__ __forceinline__ void gbar(unsigned* cnt, unsigned* rel, unsigned phase) {
  __syncthreads();
  if (threadIdx.x == 0) {
    __threadfence();
    unsigned old = __hip_atomic_fetch_add(cnt, 1u, __ATOMIC_ACQ_REL,
                                          __HIP_MEMORY_SCOPE_AGENT);
    if (old == NBLK - 1) {
      __hip_atomic_store(cnt, 0u, __ATOMIC_RELAXED, __HIP_MEMORY_SCOPE_AGENT);
      __hip_atomic_store(rel, phase, __ATOMIC_RELEASE, __HIP_MEMORY_SCOPE_AGENT);
    } else {
      while (__hip_atomic_load(rel, __ATOMIC_ACQUIRE,
                               __HIP_MEMORY_SCOPE_AGENT) < phase)
        __builtin_amdgcn_s_sleep(2);
      __threadfence();
    }
  }
  __syncthreads();
}

// flat-pool 32x32 bf16-split MFMA tile, direct-from-global (L2-resident data).
// 3-product split: hi*hi + hi*lo + lo*hi.
// mode 0: out[R*512+C]; mode 1: qh/vh head layout; mode 2: kT layout
__device__ __forceinline__ void gemm_tile32(
    const unsigned short* __restrict__ xh, const unsigned short* __restrict__ xl,
    const unsigned short* __restrict__ wh, const unsigned short* __restrict__ wl,
    const float* __restrict__ bias, float bscale,
    float* __restrict__ out, int mode, int bm, int bn, int lane)
{
  const int l15 = lane & 15, lh = lane >> 4;
  const int rA0 = bm + l15, rA1 = rA0 + 16;
  const int cB0 = bn + l15, cB1 = cB0 + 16;
  const int kb = lh << 3;
  f32x4 acc[2][2] = {};
  for (int k0 = 0; k0 < DMODEL; k0 += 32) {
    const int ko = k0 + kb;
    short8 a0h = *(const short8*)(xh + (size_t)rA0 * DMODEL + ko);
    short8 a0l = *(const short8*)(xl + (size_t)rA0 * DMODEL + ko);
    short8 a1h = *(const short8*)(xh + (size_t)rA1 * DMODEL + ko);
    short8 a1l = *(const short8*)(xl + (size_t)rA1 * DMODEL + ko);
    short8 b0h = *(const short8*)(wh + (size_t)cB0 * DMODEL + ko);
    short8 b0l = *(const short8*)(wl + (size_t)cB0 * DMODEL + ko);
    short8 b1h = *(const short8*)(wh + (size_t)cB1 * DMODEL + ko);
    short8 b1l = *(const short8*)(wl + (size_t)cB1 * DMODEL + ko);
#define MFMA_(A, B, C) C = __builtin_amdgcn_mfma_f32_16x16x32_bf16(A, B, C, 0, 0, 0)
    MFMA_(a0h, b0h, acc[0][0]); MFMA_(a0h, b0l, acc[0][0]); MFMA_(a0l, b0h, acc[0][0]);
    MFMA_(a0h, b1h, acc[0][1]); MFMA_(a0h, b1l, acc[0][1]); MFMA_(a0l, b1h, acc[0][1]);
    MFMA_(a1h, b0h, acc[1][0]); MFMA_(a1h, b0l, acc[1][0]); MFMA_(a1l, b0h, acc[1][0]);
    MFMA_(a1h, b1h, acc[1][1]); MFMA_(a1h, b1l, acc[1][1]); MFMA_(a1l, b1h, acc[1][1]);
#undef MFMA_
  }
#pragma unroll
  for (int mi = 0; mi < 2; ++mi)
#pragma unroll
    for (int ni = 0; ni < 2; ++ni) {
      const int C = bn + ni * 16 + l15;
      const float bv = bscale * bias[C];
#pragma unroll
      for (int e = 0; e < 4; ++e) {
        const int R = bm + mi * 16 + (lh << 2) + e;
        const float val = acc[mi][ni][e] + bv;
        if (mode == 0) {
          out[R * DMODEL + C] = val;
        } else {
          const int b = R >> 8, l = R & (LSEQ - 1);
          const int hh = C >> 6, dk = C & 63;
          if (mode == 1) out[((b * NHEAD + hh) * LSEQ + l) * DKH + dk] = val;
          else           out[((b * NHEAD + hh) * DKH + dk) * LSEQ + l] = val;
        }
      }
    }
}

// ---------------------------------------------------------------------------
// Mega-kernel: phase0 prep (X split + W transpose/split) | gbar |
// phase1 proj (flat wave pool) | gbar | phase2 attn | gbar | phase3 outproj.
// 256 blocks x 1024 threads, 152.25 KB LDS -> exactly 1 block/CU.
// ---------------------------------------------------------------------------
__global__ __launch_bounds__(1024, 4) void mega_kernel(
    const float* __restrict__ q, const float* __restrict__ k, const float* __restrict__ v,
    const int* __restrict__ mask,
    const float* __restrict__ Wq, const float* __restrict__ bq,
    const float* __restrict__ Wk, const float* __restrict__ bk,
    const float* __restrict__ Wv, const float* __restrict__ bv,
    const float* __restrict__ vp,
    const float* __restrict__ W0, const float* __restrict__ b0,
    unsigned short* __restrict__ xhi, unsigned short* __restrict__ xlo,
    unsigned short* __restrict__ whi, unsigned short* __restrict__ wlo,
    float* __restrict__ qh, float* __restrict__ kT, float* __restrict__ vh,
    unsigned short* __restrict__ aoh, unsigned short* __restrict__ aol,
    unsigned* __restrict__ bar,
    float* __restrict__ outp)
{
  __shared__ __align__(16) char smem[155904];
  float (*ksh)[LSEQ] = (float(*)[LSEQ])(smem);                 // 64 KB
  float (*vsh)[DKH]  = (float(*)[DKH])(smem + 65536);          // 64 KB
  float (*qsh)[DKH]  = (float(*)[DKH])(smem + 131072);         // 8 KB
  float (*psh)[LSEQ] = (float(*)[LSEQ])(smem + 139264);        // 16 KB
  float* vpsh        = (float*)(smem + 155648);                // 256 B

  const int bx = blockIdx.x;
  const int tid = threadIdx.x;
  const int lane = tid & 63, wv = tid >> 6;
  unsigned* cnt = bar;
  unsigned* rel = bar + 1;

  // ================= phase 0: prep =================
  {
    // W transpose+split: 1024 tiles of 32x32; 4 per block.
    float (*tile)[32][36] = (float(*)[32][36])smem;
    const int tsub = tid >> 8;            // 0..3
    const int sub = tid & 255;
    const int tile_id = bx * 4 + tsub;
    const int g = tile_id >> 8;
    const int rem = tile_id & 255;
    const int k0 = (rem & 15) * 32, n0 = (rem >> 4) * 32;
    const float* W = (g == 0) ? Wq : (g == 1) ? Wk : (g == 2) ? Wv : W0;
    const float scale = (g < 2) ? TWO_LOG2E : 1.0f;
    {
      const int r = sub >> 3, c = (sub & 7) << 2;
      float4 f = *(const float4*)&W[(k0 + r) * DMODEL + n0 + c];
      tile[tsub][r][c + 0] = f.x * scale;
      tile[tsub][r][c + 1] = f.y * scale;
      tile[tsub][r][c + 2] = f.z * scale;
      tile[tsub][r][c + 3] = f.w * scale;
    }
    __syncthreads();
    {
      const int n = sub >> 3, kk = (sub & 7) << 2;
      float x[4];
#pragma unroll
      for (int j = 0; j < 4; ++j) x[j] = tile[tsub][kk + j][n];
      ushort4 h4, l4;
      split4(x, h4, l4);
      const int base = (g * DMODEL + n0 + n) * DMODEL + k0 + kk;
      *(ushort4*)&whi[base] = h4;
      *(ushort4*)&wlo[base] = l4;
    }
    // X split: 3*1024*512/8 = 196608 short8 jobs
    const int idx = bx * 1024 + tid;
    if (idx < 196608) {
      const int e = idx * 8;
      const int z = e >> 19;                 // /524288
      const int off = e & 524287;
      const float* Xs = (z == 0) ? q : (z == 1) ? k : v;
      float4 f0 = *(const float4*)(Xs + off);
      float4 f1 = *(const float4*)(Xs + off + 4);
      short8 h_, l_;
      split8(f0, f1, h_, l_);
      *(short8*)(xhi + (size_t)z * 524288 + off) = h_;
      *(short8*)(xlo + (size_t)z * 524288 + off) = l_;
    }
  }
  gbar(cnt, rel, 1u);

  // ================= phase 1: proj (flat pool, 6 waves/block) =============
  if (wv < 6) {
    const int t = bx * 6 + wv;               // 0..1535
    const int g = t >> 9;                    // /512
    const int r512 = t & 511;
    const int bm = (r512 & 31) << 5, bn = (r512 >> 5) << 5;
    const unsigned short* xh = xhi + (size_t)g * 524288;
    const unsigned short* xl = xlo + (size_t)g * 524288;
    const unsigned short* wh = whi + (size_t)g * 262144;
    const unsigned short* wl = wlo + (size_t)g * 262144;
    const float* bias = (g == 0) ? bq : (g == 1) ? bk : bv;
    const float bscale = (g < 2) ? TWO_LOG2E : 1.0f;
    float* out = (g == 0) ? qh : (g == 1) ? kT : vh;
    const int mode = (g == 1) ? 2 : 1;
    gemm_tile32(xh, xl, wh, wl, bias, bscale, out, mode, bm, bn, lane);
  }
  gbar(cnt, rel, 2u);

  // ================= phase 2: attn =================
  {
    const int bh = bx >> 3;                  // 0..31
    const int b = bh >> 3, h = bh & 7;
    const int i0 = (bx & 7) << 5;

    const float* kbase = kT + (size_t)bh * DKH * LSEQ;
    for (int t = tid; t < DKH * LSEQ / 4; t += 1024) {
      const int d = t >> 6, j4 = (t & 63) << 2;
      *(float4*)&ksh[d][j4] = *(const float4*)&kbase[d * LSEQ + j4];
    }
    const float* vbase = vh + (size_t)bh * LSEQ * DKH;
    for (int t = tid; t < LSEQ * DKH / 4; t += 1024) {
      const int j = t >> 4, d4 = (t & 15) << 2;
      *(float4*)&vsh[j][d4] = *(const float4*)&vbase[j * DKH + d4];
    }
    if (tid < 512) {
      const float* qbase = qh + ((size_t)bh * LSEQ + i0) * DKH;
      const int r = tid >> 4, d4 = (tid & 15) << 2;
      *(float4*)&qsh[r][d4] = *(const float4*)&qbase[r * DKH + d4];
    }
    if (tid < DKH) vpsh[tid] = vp[h * DKH + tid];
    __syncthreads();

    float tj[2][4] = {};
#pragma unroll 2
    for (int g = 0; g < 16; ++g) {
      float kv[16];
#pragma unroll
      for (int t = 0; t < 4; ++t)
#pragma unroll
        for (int c = 0; c < 4; ++c)
          kv[t * 4 + c] = ksh[(g << 2) + t][(c << 6) + lane];
      float vpv[4];
      *(float4*)vpv = *(const float4*)&vpsh[g << 2];
#pragma unroll
      for (int r = 0; r < 2; ++r) {
        float q_[4];
        *(float4*)q_ = *(const float4*)&qsh[(wv << 1) + r][g << 2];
#pragma unroll
        for (int t = 0; t < 4; ++t)
#pragma unroll
          for (int c = 0; c < 4; ++c) {
            const float x = q_[t] + kv[t * 4 + c];
            const float e = __builtin_amdgcn_exp2f(x);
            tj[r][c] = fmaf(vpv[t], __builtin_amdgcn_rcpf(e + 1.f), tj[r][c]);
          }
      }
    }

    const int cg = lane >> 4, qq = lane & 15;
#pragma unroll
    for (int r = 0; r < 2; ++r) {
      const int i = i0 + (wv << 1) + r;
      const int* mrow = mask + ((size_t)b * LSEQ + i) * LSEQ;
      float t4[4];
#pragma unroll
      for (int c = 0; c < 4; ++c) {
        const int mv = mrow[(c << 6) + lane];
        t4[c] = mv ? tj[r][c] : 1.0e9f;
      }
      float m = fminf(fminf(t4[0], t4[1]), fminf(t4[2], t4[3]));
#pragma unroll
      for (int off = 32; off; off >>= 1) m = fminf(m, __shfl_xor(m, off));
      const float m2 = m * TWO_LOG2E;
      float p[4];
      float sum = 0.f;
#pragma unroll
      for (int c = 0; c < 4; ++c) {
        p[c] = __builtin_amdgcn_exp2f(fmaf(t4[c], -TWO_LOG2E, m2));
        sum += p[c];
      }
#pragma unroll
      for (int off = 32; off; off >>= 1) sum += __shfl_xor(sum, off);
      const float rs = __builtin_amdgcn_rcpf(sum);
#pragma unroll
      for (int c = 0; c < 4; ++c) psh[wv][(c << 6) + lane] = p[c];

      float o[4] = {0.f, 0.f, 0.f, 0.f};
#pragma unroll 4
      for (int jg = 0; jg < 16; ++jg) {
        float pv[4];
        *(float4*)pv = *(const float4*)&psh[wv][(cg << 6) + (jg << 2)];
#pragma unroll
        for (int t = 0; t < 4; ++t) {
          float v_[4];
          *(float4*)v_ = *(const float4*)&vsh[(cg << 6) + (jg << 2) + t][qq << 2];
#pragma unroll
          for (int u = 0; u < 4; ++u) o[u] = fmaf(pv[t], v_[u], o[u]);
        }
      }
#pragma unroll
      for (int off = 16; off <= 32; off <<= 1) {
#pragma unroll
        for (int u = 0; u < 4; ++u) o[u] += __shfl_xor(o[u], off);
      }
      if (lane < 16) {
        float ov[4];
#pragma unroll
        for (int u = 0; u < 4; ++u) ov[u] = o[u] * rs;
        ushort4 h4, l4;
        split4(ov, h4, l4);
        const int base = ((size_t)b * LSEQ + i) * DMODEL + h * DKH + (qq << 2);
        *(ushort4*)&aoh[base] = h4;
        *(ushort4*)&aol[base] = l4;
      }
    }
  }
  gbar(cnt, rel, 3u);

  // ================= phase 3: outproj (512 tiles, 2 waves/block) ==========
  if (wv == 0 || wv == 2) {
    const int t = bx * 2 + (wv >> 1);        // 0..511
    const int bm = (t & 31) << 5, bn = (t >> 5) << 5;
    gemm_tile32(aoh, aol, whi + (size_t)3 * 262144, wlo + (size_t)3 * 262144,
                b0, 1.0f, outp, 0, bm, bn, lane);
  }
}

// ---------------------------------------------------------------------------
extern "C" void kernel_launch(void* const* d_in, const int* in_sizes, int n_in,
                              void* d_out, int out_size, void* d_ws, size_t ws_size,
                              hipStream_t stream) {
  const float* q   = (const float*)d_in[0];
  const float* k   = (const float*)d_in[1];
  const float* v   = (const float*)d_in[2];
  const int*  mask = (const int*)d_in[3];
  const float* Wq  = (const float*)d_in[4];
  const float* bq  = (const float*)d_in[5];
  const float* Wk  = (const float*)d_in[6];
  const float* bk  = (const float*)d_in[7];
  const float* Wv  = (const float*)d_in[8];
  const float* bv  = (const float*)d_in[9];
  const float* vp  = (const float*)d_in[10];
  const float* W0  = (const float*)d_in[11];
  const float* b0  = (const float*)d_in[12];
  float* outp = (float*)d_out;

  char* wsb = (char*)d_ws;
  unsigned short* whi = (unsigned short*)(wsb);               // 2 MB
  unsigned short* wlo = (unsigned short*)(wsb + (2u << 20));  // 2 MB
  unsigned short* xhi = (unsigned short*)(wsb + (4u << 20));  // 3 MB
  unsigned short* xlo = (unsigned short*)(wsb + (7u << 20));  // 3 MB
  float* qh = (float*)(wsb + (10u << 20));                    // 2 MB
  float* kT = (float*)(wsb + (12u << 20));                    // 2 MB
  float* vh = (float*)(wsb + (14u << 20));                    // 2 MB
  unsigned short* aoh = (unsigned short*)(wsb + (16u << 20)); // 1 MB
  unsigned short* aol = (unsigned short*)(wsb + (17u << 20)); // 1 MB
  unsigned* bar = (unsigned*)(wsb + (18u << 20));

  init_kernel<<<1, 1, 0, stream>>>(bar);
  mega_kernel<<<NBLK, 1024, 0, stream>>>(q, k, v, mask, Wq, bq, Wk, bk, Wv, bv,
                                         vp, W0, b0, xhi, xlo, whi, wlo,
                                         qh, kT, vh, aoh, aol, bar, outp);
}

// Round 9
// 162.361 us; speedup vs baseline: 1.6440x; 1.6440x over previous
//
#include <hip/hip_runtime.h>

#define LSEQ 256
#define DMODEL 512
#define NHEAD 8
#define DKH 64
#define BATCH 4

#define TWO_LOG2E 2.885390081777927f

using short8 = __attribute__((ext_vector_type(8))) short;
using f32x4  = __attribute__((ext_vector_type(4))) float;

// split fp32 -> truncated bf16 hi + bf16(lo remainder)
__device__ __forceinline__ void split4(const float* f, ushort4& h, ushort4& l) {
  unsigned short hh[4], ll[4];
#pragma unroll
  for (int j = 0; j < 4; ++j) {
    unsigned int u = __float_as_uint(f[j]);
    hh[j] = (unsigned short)(u >> 16);
    float hf = __uint_as_float(u & 0xFFFF0000u);
    ll[j] = (unsigned short)(__float_as_uint(f[j] - hf) >> 16);
  }
  h = make_ushort4(hh[0], hh[1], hh[2], hh[3]);
  l = make_ushort4(ll[0], ll[1], ll[2], ll[3]);
}

// ---------------------------------------------------------------------------
// prep: z=0..2 -> convert X (q,k,v) to bf16 hi/lo [z][1024][512] (linear)
//       z=3..6 -> convert+transpose W (Wq,Wk,Wv,W0) to [g][n][k] hi/lo
//                 (Wq,Wk prescaled by 2*log2e)
// ---------------------------------------------------------------------------
__global__ __launch_bounds__(256) void prep_kernel(
    const float* __restrict__ q, const float* __restrict__ k, const float* __restrict__ v,
    const float* __restrict__ Wq, const float* __restrict__ Wk,
    const float* __restrict__ Wv, const float* __restrict__ W0,
    unsigned short* __restrict__ xhi, unsigned short* __restrict__ xlo,
    unsigned short* __restrict__ whi, unsigned short* __restrict__ wlo)
{
  const int z = blockIdx.z;
  const int tid = threadIdx.x;
  if (z < 3) {
    const float* X = (z == 0) ? q : (z == 1) ? k : v;
    const int r = blockIdx.x * 32 + (tid >> 3);
    const int c = blockIdx.y * 32 + ((tid & 7) << 2);
    float4 f = *(const float4*)&X[r * DMODEL + c];
    ushort4 h4, l4;
    split4((const float*)&f, h4, l4);
    const int base = (z * 1024 + r) * DMODEL + c;
    *(ushort4*)&xhi[base] = h4;
    *(ushort4*)&xlo[base] = l4;
  } else {
    if (blockIdx.x >= 16) return;
    const int g = z - 3;
    const float* W = (g == 0) ? Wq : (g == 1) ? Wk : (g == 2) ? Wv : W0;
    const float scale = (g < 2) ? TWO_LOG2E : 1.0f;
    const int k0 = blockIdx.x * 32, n0 = blockIdx.y * 32;
    __shared__ float tile[32][36];
    {
      const int r = tid >> 3, c = (tid & 7) << 2;
      float4 f = *(const float4*)&W[(k0 + r) * DMODEL + n0 + c];
      tile[r][c + 0] = f.x * scale;
      tile[r][c + 1] = f.y * scale;
      tile[r][c + 2] = f.z * scale;
      tile[r][c + 3] = f.w * scale;
    }
    __syncthreads();
    const int n = tid >> 3, kk = (tid & 7) << 2;
    float x[4];
#pragma unroll
    for (int j = 0; j < 4; ++j) x[j] = tile[kk + j][n];
    ushort4 h4, l4;
    split4(x, h4, l4);
    const int base = (g * DMODEL + n0 + n) * DMODEL + k0 + kk;
    *(ushort4*)&whi[base] = h4;
    *(ushort4*)&wlo[base] = l4;
  }
}

// ---------------------------------------------------------------------------
// K-split partial GEMM wave body: one 32x32 tile x one K=128 slice per wave.
// Direct-from-global fragment loads (latency hidden by 4-6 waves/SIMD TLP).
// 3-product bf16 split: hi*hi + hi*lo + lo*hi. Partials fp32, no bias.
// ---------------------------------------------------------------------------
__device__ __forceinline__ void gemm_partial32(
    const unsigned short* __restrict__ xh, const unsigned short* __restrict__ xl,
    const unsigned short* __restrict__ wh, const unsigned short* __restrict__ wl,
    float* __restrict__ pb, int bm, int bn, int k0, int lane)
{
  const int l15 = lane & 15, lh = lane >> 4;
  const int rA0 = bm + l15, rA1 = rA0 + 16;
  const int cB0 = bn + l15, cB1 = cB0 + 16;
  f32x4 acc[2][2] = {};
#pragma unroll 2
  for (int s = 0; s < 4; ++s) {
    const int ko = k0 + s * 32 + (lh << 3);
    short8 a0h = *(const short8*)(xh + (size_t)rA0 * DMODEL + ko);
    short8 a0l = *(const short8*)(xl + (size_t)rA0 * DMODEL + ko);
    short8 a1h = *(const short8*)(xh + (size_t)rA1 * DMODEL + ko);
    short8 a1l = *(const short8*)(xl + (size_t)rA1 * DMODEL + ko);
    short8 b0h = *(const short8*)(wh + (size_t)cB0 * DMODEL + ko);
    short8 b0l = *(const short8*)(wl + (size_t)cB0 * DMODEL + ko);
    short8 b1h = *(const short8*)(wh + (size_t)cB1 * DMODEL + ko);
    short8 b1l = *(const short8*)(wl + (size_t)cB1 * DMODEL + ko);
#define MFMA_(A, B, C) C = __builtin_amdgcn_mfma_f32_16x16x32_bf16(A, B, C, 0, 0, 0)
    MFMA_(a0h, b0h, acc[0][0]); MFMA_(a0h, b0l, acc[0][0]); MFMA_(a0l, b0h, acc[0][0]);
    MFMA_(a0h, b1h, acc[0][1]); MFMA_(a0h, b1l, acc[0][1]); MFMA_(a0l, b1h, acc[0][1]);
    MFMA_(a1h, b0h, acc[1][0]); MFMA_(a1h, b0l, acc[1][0]); MFMA_(a1l, b0h, acc[1][0]);
    MFMA_(a1h, b1h, acc[1][1]); MFMA_(a1h, b1l, acc[1][1]); MFMA_(a1l, b1h, acc[1][1]);
#undef MFMA_
  }
#pragma unroll
  for (int mi = 0; mi < 2; ++mi)
#pragma unroll
    for (int ni = 0; ni < 2; ++ni) {
      const int C = bn + ni * 16 + l15;
#pragma unroll
      for (int e = 0; e < 4; ++e) {
        const int R = bm + mi * 16 + (lh << 2) + e;
        pb[(size_t)R * DMODEL + C] = acc[mi][ni][e];
      }
    }
}

// proj partials: 1536 blocks (=tile), 4 waves = 4 K-slices.
// pbuf[((ks*3+z)<<19) + R*512 + C]
__global__ __launch_bounds__(256, 4) void projp_kernel(
    const unsigned short* __restrict__ xhi, const unsigned short* __restrict__ xlo,
    const unsigned short* __restrict__ whi, const unsigned short* __restrict__ wlo,
    float* __restrict__ pbuf)
{
  const int bx = blockIdx.x;              // 0..1535
  const int z = bx >> 9, r = bx & 511;
  const int bm = (r >> 4) << 5, bn = (r & 15) << 5;
  const int wv = threadIdx.x >> 6, lane = threadIdx.x & 63;
  gemm_partial32(xhi + (size_t)z * 524288, xlo + (size_t)z * 524288,
                 whi + (size_t)z * 262144, wlo + (size_t)z * 262144,
                 pbuf + ((size_t)(wv * 3 + z) << 19), bm, bn, wv << 7, lane);
}

// reduce proj partials -> qh/kh/vh in head layout [(b*8+h)*256+l][dk], scaled
__global__ __launch_bounds__(256) void reduceqkv_kernel(
    const float* __restrict__ pbuf,
    const float* __restrict__ bq, const float* __restrict__ bk,
    const float* __restrict__ bv,
    float* __restrict__ qh, float* __restrict__ kh, float* __restrict__ vh)
{
  const int e0 = (blockIdx.x * 256 + threadIdx.x) * 8;   // grid 768
  const int z = e0 >> 19;
  const int rem = e0 & 524287;
  const int R = rem >> 9, C = rem & 511;
  float s[8] = {};
#pragma unroll
  for (int ks = 0; ks < 4; ++ks) {
    const float* p = pbuf + (((size_t)(ks * 3 + z)) << 19) + rem;
    float4 a = *(const float4*)p;
    float4 b = *(const float4*)(p + 4);
    s[0] += a.x; s[1] += a.y; s[2] += a.z; s[3] += a.w;
    s[4] += b.x; s[5] += b.y; s[6] += b.z; s[7] += b.w;
  }
  const float* bias = (z == 0) ? bq : (z == 1) ? bk : bv;
  const float scale = (z < 2) ? TWO_LOG2E : 1.0f;
#pragma unroll
  for (int j = 0; j < 8; ++j) s[j] = (s[j] + scale * bias[C + j]) * ((z < 2) ? 1.0f : 1.0f);
  // note: bias prescale folded: (x*scale' ... ) — W was prescaled in prep, so
  // partials are already scaled for z<2; bias must be scaled too (done above).
  const int b_ = R >> 8, l_ = R & 255;
  const int h_ = C >> 6, dk = C & 63;
  float* dst = ((z == 0) ? qh : (z == 1) ? kh : vh) +
               (((size_t)(b_ * NHEAD + h_) * LSEQ + l_) * DKH + dk);
  *(float4*)dst = make_float4(s[0], s[1], s[2], s[3]);
  *(float4*)(dst + 4) = make_float4(s[4], s[5], s[6], s[7]);
}

// outproj partials: 512 blocks (=tile), 4 waves = 4 K-slices.
__global__ __launch_bounds__(256, 4) void outp_kernel(
    const unsigned short* __restrict__ aoh, const unsigned short* __restrict__ aol,
    const unsigned short* __restrict__ whi, const unsigned short* __restrict__ wlo,
    float* __restrict__ pbufo)
{
  const int bx = blockIdx.x;              // 0..511
  const int bm = (bx >> 4) << 5, bn = (bx & 15) << 5;
  const int wv = threadIdx.x >> 6, lane = threadIdx.x & 63;
  gemm_partial32(aoh, aol, whi + (size_t)3 * 262144, wlo + (size_t)3 * 262144,
                 pbufo + ((size_t)wv << 19), bm, bn, wv << 7, lane);
}

__global__ __launch_bounds__(256) void reduceout_kernel(
    const float* __restrict__ pbufo, const float* __restrict__ b0,
    float* __restrict__ outp)
{
  const int e0 = (blockIdx.x * 256 + threadIdx.x) * 8;   // grid 256
  const int C = e0 & 511;
  float s[8] = {};
#pragma unroll
  for (int ks = 0; ks < 4; ++ks) {
    const float* p = pbufo + (((size_t)ks) << 19) + e0;
    float4 a = *(const float4*)p;
    float4 b = *(const float4*)(p + 4);
    s[0] += a.x; s[1] += a.y; s[2] += a.z; s[3] += a.w;
    s[4] += b.x; s[5] += b.y; s[6] += b.z; s[7] += b.w;
  }
#pragma unroll
  for (int j = 0; j < 8; ++j) s[j] += b0[C + j];
  *(float4*)(outp + e0) = make_float4(s[0], s[1], s[2], s[3]);
  *(float4*)(outp + e0 + 4) = make_float4(s[4], s[5], s[6], s[7]);
}

// ---------------------------------------------------------------------------
// Fused Bahdanau attention. qh,kh prescaled by 2*log2e (+scaled bias).
// t_j = sum_d vp_d * rcp(exp2(q'+k') + 1); softmax in t-space:
// p = exp2(-2log2e*(t - min t)); masked -> t = +1e9.
// 1024 threads / 16 waves, 2 q-rows per wave; 152 KB LDS, 4 waves/SIMD.
// K staged [j][d] with XOR-swizzled float4 chunks -> ds_read_b128 score loads.
// ---------------------------------------------------------------------------
__global__ __launch_bounds__(1024, 4) void attn_kernel(
    const float* __restrict__ qh,   // (B,H,L,DK) prescaled
    const float* __restrict__ kh,   // (B,H,L,DK) prescaled
    const float* __restrict__ vh,   // (B,H,L,DK)
    const int* __restrict__ mask,   // (B,L,L)
    const float* __restrict__ vp,   // (H,DK)
    unsigned short* __restrict__ aoh,  // (B*L, D) bf16 hi
    unsigned short* __restrict__ aol)  // (B*L, D) bf16 lo
{
  __shared__ float kshf[DKH * LSEQ];    // 64 KB, [j][chunk^(j&15)] float4s
  __shared__ float vsh[LSEQ][DKH];      // 64 KB
  __shared__ float qsh[32][DKH];        // 8 KB
  __shared__ float psh[16][LSEQ];       // 16 KB
  __shared__ float vpsh[DKH];

  const int bh = blockIdx.x;            // b*8+h
  const int b = bh >> 3, h = bh & 7;
  const int i0 = blockIdx.y * 32;
  const int tid = threadIdx.x;
  const int lane = tid & 63, wv = tid >> 6;   // 16 waves

  const float* kbase = kh + (size_t)bh * LSEQ * DKH;
  for (int t = tid; t < LSEQ * DKH / 4; t += 1024) {
    const int j = t >> 4, c4 = t & 15;
    *(float4*)&kshf[(j << 6) + ((c4 ^ (j & 15)) << 2)] =
        *(const float4*)&kbase[(j << 6) + (c4 << 2)];
  }
  const float* vbase = vh + (size_t)bh * LSEQ * DKH;
  for (int t = tid; t < LSEQ * DKH / 4; t += 1024) {
    const int j = t >> 4, d4 = (t & 15) << 2;
    *(float4*)&vsh[j][d4] = *(const float4*)&vbase[j * DKH + d4];
  }
  if (tid < 512) {
    const float* qbase = qh + ((size_t)bh * LSEQ + i0) * DKH;
    const int r = tid >> 4, d4 = (tid & 15) << 2;
    *(float4*)&qsh[r][d4] = *(const float4*)&qbase[r * DKH + d4];
  }
  if (tid < DKH) vpsh[tid] = vp[h * DKH + tid];
  __syncthreads();

  // ---- score phase: 2 rows per wave, b128 K reads ----
  float tj[2][4] = {};
#pragma unroll 2
  for (int g = 0; g < 16; ++g) {
    float vpv[4], q0[4], q1[4];
    *(float4*)vpv = *(const float4*)&vpsh[g << 2];
    *(float4*)q0 = *(const float4*)&qsh[(wv << 1) + 0][g << 2];
    *(float4*)q1 = *(const float4*)&qsh[(wv << 1) + 1][g << 2];
#pragma unroll
    for (int c = 0; c < 4; ++c) {
      const int j = (c << 6) + lane;
      float kv[4];
      *(float4*)kv = *(const float4*)&kshf[(j << 6) + ((g ^ (j & 15)) << 2)];
#pragma unroll
      for (int t = 0; t < 4; ++t) {
        const float x0 = q0[t] + kv[t];
        const float e0 = __builtin_amdgcn_exp2f(x0);
        tj[0][c] = fmaf(vpv[t], __builtin_amdgcn_rcpf(e0 + 1.f), tj[0][c]);
        const float x1 = q1[t] + kv[t];
        const float e1 = __builtin_amdgcn_exp2f(x1);
        tj[1][c] = fmaf(vpv[t], __builtin_amdgcn_rcpf(e1 + 1.f), tj[1][c]);
      }
    }
  }

  // ---- per-row: mask, softmax (t-space), PV ----
  const int cg = lane >> 4, qq = lane & 15;
#pragma unroll
  for (int r = 0; r < 2; ++r) {
    const int i = i0 + (wv << 1) + r;
    const int* mrow = mask + ((size_t)b * LSEQ + i) * LSEQ;
    float t4[4];
#pragma unroll
    for (int c = 0; c < 4; ++c) {
      const int mv = mrow[(c << 6) + lane];
      t4[c] = mv ? tj[r][c] : 1.0e9f;
    }
    float m = fminf(fminf(t4[0], t4[1]), fminf(t4[2], t4[3]));
#pragma unroll
    for (int off = 32; off; off >>= 1) m = fminf(m, __shfl_xor(m, off));
    const float m2 = m * TWO_LOG2E;
    float p[4];
    float sum = 0.f;
#pragma unroll
    for (int c = 0; c < 4; ++c) {
      p[c] = __builtin_amdgcn_exp2f(fmaf(t4[c], -TWO_LOG2E, m2));
      sum += p[c];
    }
#pragma unroll
    for (int off = 32; off; off >>= 1) sum += __shfl_xor(sum, off);
    const float rs = __builtin_amdgcn_rcpf(sum);
#pragma unroll
    for (int c = 0; c < 4; ++c) psh[wv][(c << 6) + lane] = p[c];

    float o[4] = {0.f, 0.f, 0.f, 0.f};
#pragma unroll 4
    for (int jg = 0; jg < 16; ++jg) {
      float pv[4];
      *(float4*)pv = *(const float4*)&psh[wv][(cg << 6) + (jg << 2)];
#pragma unroll
      for (int t = 0; t < 4; ++t) {
        float v_[4];
        *(float4*)v_ = *(const float4*)&vsh[(cg << 6) + (jg << 2) + t][qq << 2];
#pragma unroll
        for (int u = 0; u < 4; ++u) o[u] = fmaf(pv[t], v_[u], o[u]);
      }
    }
#pragma unroll
    for (int off = 16; off <= 32; off <<= 1) {
#pragma unroll
      for (int u = 0; u < 4; ++u) o[u] += __shfl_xor(o[u], off);
    }
    if (lane < 16) {
      float ov[4];
#pragma unroll
      for (int u = 0; u < 4; ++u) ov[u] = o[u] * rs;
      ushort4 h4, l4;
      split4(ov, h4, l4);
      const int base = ((size_t)b * LSEQ + i) * DMODEL + h * DKH + (qq << 2);
      *(ushort4*)&aoh[base] = h4;
      *(ushort4*)&aol[base] = l4;
    }
  }
}

// ---------------------------------------------------------------------------
extern "C" void kernel_launch(void* const* d_in, const int* in_sizes, int n_in,
                              void* d_out, int out_size, void* d_ws, size_t ws_size,
                              hipStream_t stream) {
  const float* q   = (const float*)d_in[0];
  const float* k   = (const float*)d_in[1];
  const float* v   = (const float*)d_in[2];
  const int*  mask = (const int*)d_in[3];
  const float* Wq  = (const float*)d_in[4];
  const float* bq  = (const float*)d_in[5];
  const float* Wk  = (const float*)d_in[6];
  const float* bk  = (const float*)d_in[7];
  const float* Wv  = (const float*)d_in[8];
  const float* bv  = (const float*)d_in[9];
  const float* vp  = (const float*)d_in[10];
  const float* W0  = (const float*)d_in[11];
  const float* b0  = (const float*)d_in[12];
  float* outp = (float*)d_out;

  char* wsb = (char*)d_ws;
  unsigned short* whi = (unsigned short*)(wsb);                // 0-2 MB
  unsigned short* wlo = (unsigned short*)(wsb + (2u << 20));   // 2-4 MB
  unsigned short* xhi = (unsigned short*)(wsb + (4u << 20));   // 4-7 MB
  unsigned short* xlo = (unsigned short*)(wsb + (7u << 20));   // 7-10 MB
  float* qh = (float*)(wsb + (10u << 20));                     // 10-12 MB
  float* kh = (float*)(wsb + (12u << 20));                     // 12-14 MB
  float* vh = (float*)(wsb + (14u << 20));                     // 14-16 MB
  unsigned short* aoh = (unsigned short*)(wsb + (16u << 20));  // 16-17 MB
  unsigned short* aol = (unsigned short*)(wsb + (17u << 20));  // 17-18 MB
  float* pbuf  = (float*)(wsb + (18u << 20));                  // 18-42 MB
  float* pbufo = (float*)(wsb + (42u << 20));                  // 42-50 MB

  prep_kernel<<<dim3(32, 16, 7), 256, 0, stream>>>(q, k, v, Wq, Wk, Wv, W0,
                                                   xhi, xlo, whi, wlo);
  projp_kernel<<<1536, 256, 0, stream>>>(xhi, xlo, whi, wlo, pbuf);
  reduceqkv_kernel<<<768, 256, 0, stream>>>(pbuf, bq, bk, bv, qh, kh, vh);
  attn_kernel<<<dim3(32, 8), 1024, 0, stream>>>(qh, kh, vh, mask, vp, aoh, aol);
  outp_kernel<<<512, 256, 0, stream>>>(aoh, aol, whi, wlo, pbufo);
  reduceout_kernel<<<256, 256, 0, stream>>>(pbufo, b0, outp);
}

// Round 10
// 138.209 us; speedup vs baseline: 1.9313x; 1.1747x over previous
//
#include <hip/hip_runtime.h>

#define LSEQ 256
#define DMODEL 512
#define NHEAD 8
#define DKH 64
#define BATCH 4

#define TWO_LOG2E 2.885390081777927f

using short8 = __attribute__((ext_vector_type(8))) short;
using f32x4  = __attribute__((ext_vector_type(4))) float;

// split fp32 -> truncated bf16 hi + bf16(lo remainder)
__device__ __forceinline__ void split4(const float* f, ushort4& h, ushort4& l) {
  unsigned short hh[4], ll[4];
#pragma unroll
  for (int j = 0; j < 4; ++j) {
    unsigned int u = __float_as_uint(f[j]);
    hh[j] = (unsigned short)(u >> 16);
    float hf = __uint_as_float(u & 0xFFFF0000u);
    ll[j] = (unsigned short)(__float_as_uint(f[j] - hf) >> 16);
  }
  h = make_ushort4(hh[0], hh[1], hh[2], hh[3]);
  l = make_ushort4(ll[0], ll[1], ll[2], ll[3]);
}

__device__ __forceinline__ void split8(float4 f0, float4 f1, short8& h, short8& l) {
  float f[8] = {f0.x, f0.y, f0.z, f0.w, f1.x, f1.y, f1.z, f1.w};
#pragma unroll
  for (int j = 0; j < 8; ++j) {
    unsigned int u = __float_as_uint(f[j]);
    h[j] = (short)(u >> 16);
    float hf = __uint_as_float(u & 0xFFFF0000u);
    l[j] = (short)(__float_as_uint(f[j] - hf) >> 16);
  }
}

// ---------------------------------------------------------------------------
// prep_w: convert+transpose W (Wq,Wk,Wv,W0) to [g][n][k] bf16 hi/lo.
// Wq,Wk prescaled by 2*log2e. grid (16,16,4): k0=bx*32, n0=by*32, g=z.
// ---------------------------------------------------------------------------
__global__ __launch_bounds__(256) void prep_w_kernel(
    const float* __restrict__ Wq, const float* __restrict__ Wk,
    const float* __restrict__ Wv, const float* __restrict__ W0,
    unsigned short* __restrict__ whi, unsigned short* __restrict__ wlo)
{
  const int tid = threadIdx.x;
  const int g = blockIdx.z;
  const float* W = (g == 0) ? Wq : (g == 1) ? Wk : (g == 2) ? Wv : W0;
  const float scale = (g < 2) ? TWO_LOG2E : 1.0f;
  const int k0 = blockIdx.x * 32, n0 = blockIdx.y * 32;
  __shared__ float tile[32][36];
  {
    const int r = tid >> 3, c = (tid & 7) << 2;
    float4 f = *(const float4*)&W[(k0 + r) * DMODEL + n0 + c];
    tile[r][c + 0] = f.x * scale;
    tile[r][c + 1] = f.y * scale;
    tile[r][c + 2] = f.z * scale;
    tile[r][c + 3] = f.w * scale;
  }
  __syncthreads();
  const int n = tid >> 3, kk = (tid & 7) << 2;
  float x[4];
#pragma unroll
  for (int j = 0; j < 4; ++j) x[j] = tile[kk + j][n];
  ushort4 h4, l4;
  split4(x, h4, l4);
  const int base = (g * DMODEL + n0 + n) * DMODEL + k0 + kk;
  *(ushort4*)&whi[base] = h4;
  *(ushort4*)&wlo[base] = l4;
}

// ---------------------------------------------------------------------------
// Double-buffered bf16-split MFMA GEMM, fp32 A source (split during staging).
// Block tile 64x64, BK=64, 4 waves (32x32 quadrant each). One barrier/step.
// LDS [buf][Ah,Al,Bh,Bl][row*8+chunk], chunk XOR (row&7) both-sides.
// 3-product split: hi*hi + hi*lo + lo*hi.
// mode 0: out[R*512+C]; mode 1: head layout [((b*8+h)*256+l)*64+dk]
// ---------------------------------------------------------------------------
__device__ __forceinline__ void gemm_fp32A(
    const float* __restrict__ X,
    const unsigned short* __restrict__ wh, const unsigned short* __restrict__ wl,
    const float* __restrict__ bias, float bscale,
    float* __restrict__ out, int mode, int bx, int by)
{
  __shared__ short8 lds[2][4][512];   // 64 KB
  const int tid = threadIdx.x;
  const int lane = tid & 63, w = tid >> 6;
  const int bm0 = bx * 64, bn0 = by * 64;

  const int r0 = tid >> 3, c0 = tid & 7, g0 = c0 ^ (r0 & 7);
  const int r1 = r0 + 32,  g1 = c0 ^ (r1 & 7);
  const size_t aoff0 = (size_t)(bm0 + r0) * DMODEL + g0 * 8;
  const size_t aoff1 = (size_t)(bm0 + r1) * DMODEL + g1 * 8;
  const size_t boff0 = (size_t)(bn0 + r0) * DMODEL + g0 * 8;
  const size_t boff1 = (size_t)(bn0 + r1) * DMODEL + g1 * 8;

  const int mrb = (w >> 1) << 5, ncb = (w & 1) << 5;
  const int l15 = lane & 15, lh = lane >> 4, l7 = lane & 7;

  float4 af00, af01, af10, af11;
  short8 b0h, b0l, b1h, b1l;

#define LOADS(K)                                                  \
  { af00 = *(const float4*)(X + aoff0 + (K));                     \
    af01 = *(const float4*)(X + aoff0 + (K) + 4);                 \
    af10 = *(const float4*)(X + aoff1 + (K));                     \
    af11 = *(const float4*)(X + aoff1 + (K) + 4);                 \
    b0h = *(const short8*)(wh + boff0 + (K));                     \
    b0l = *(const short8*)(wl + boff0 + (K));                     \
    b1h = *(const short8*)(wh + boff1 + (K));                     \
    b1l = *(const short8*)(wl + boff1 + (K)); }
#define WRITES(BUF)                                               \
  { short8 h_, l_;                                                \
    split8(af00, af01, h_, l_);                                   \
    lds[BUF][0][tid] = h_; lds[BUF][1][tid] = l_;                 \
    split8(af10, af11, h_, l_);                                   \
    lds[BUF][0][tid + 256] = h_; lds[BUF][1][tid + 256] = l_;     \
    lds[BUF][2][tid] = b0h; lds[BUF][3][tid] = b0l;               \
    lds[BUF][2][tid + 256] = b1h; lds[BUF][3][tid + 256] = b1l; }

  f32x4 acc[2][2] = {};
  LOADS(0);
  WRITES(0);
  __syncthreads();

  int cur = 0;
  for (int t = 0; t < 8; ++t) {
    if (t < 7) LOADS((t + 1) * 64);
#pragma unroll
    for (int s = 0; s < 2; ++s) {
      const int chb = (s << 2) + lh;
      const int ra0 = (mrb + l15) * 8 + (chb ^ l7);
      const int ra1 = (mrb + 16 + l15) * 8 + (chb ^ l7);
      const int rb0 = (ncb + l15) * 8 + (chb ^ l7);
      const int rb1 = (ncb + 16 + l15) * 8 + (chb ^ l7);
      short8 a0h = lds[cur][0][ra0], a0l = lds[cur][1][ra0];
      short8 a1h = lds[cur][0][ra1], a1l = lds[cur][1][ra1];
      short8 w0h = lds[cur][2][rb0], w0l = lds[cur][3][rb0];
      short8 w1h = lds[cur][2][rb1], w1l = lds[cur][3][rb1];
#define MFMA_(A, B, C) C = __builtin_amdgcn_mfma_f32_16x16x32_bf16(A, B, C, 0, 0, 0)
      MFMA_(a0h, w0h, acc[0][0]); MFMA_(a0h, w0l, acc[0][0]); MFMA_(a0l, w0h, acc[0][0]);
      MFMA_(a0h, w1h, acc[0][1]); MFMA_(a0h, w1l, acc[0][1]); MFMA_(a0l, w1h, acc[0][1]);
      MFMA_(a1h, w0h, acc[1][0]); MFMA_(a1h, w0l, acc[1][0]); MFMA_(a1l, w0h, acc[1][0]);
      MFMA_(a1h, w1h, acc[1][1]); MFMA_(a1h, w1l, acc[1][1]); MFMA_(a1l, w1h, acc[1][1]);
#undef MFMA_
    }
    if (t < 7) WRITES(cur ^ 1);
    __syncthreads();
    cur ^= 1;
  }
#undef LOADS
#undef WRITES

  const int bm = bm0 + mrb, bn = bn0 + ncb;
#pragma unroll
  for (int mi = 0; mi < 2; ++mi)
#pragma unroll
    for (int ni = 0; ni < 2; ++ni) {
      const int C = bn + ni * 16 + l15;
      const float bv = bscale * bias[C];
#pragma unroll
      for (int e = 0; e < 4; ++e) {
        const int R = bm + mi * 16 + (lh << 2) + e;
        const float val = acc[mi][ni][e] + bv;
        if (mode == 0) {
          out[R * DMODEL + C] = val;
        } else {
          const int b = R >> 8, l = R & (LSEQ - 1);
          const int hh = C >> 6, dk = C & 63;
          out[((b * NHEAD + hh) * LSEQ + l) * DKH + dk] = val;
        }
      }
    }
}

// same skeleton, pre-split bf16 A source (short8 loads, no in-kernel split)
__device__ __forceinline__ void gemm_splitA(
    const unsigned short* __restrict__ xh, const unsigned short* __restrict__ xl,
    const unsigned short* __restrict__ wh, const unsigned short* __restrict__ wl,
    const float* __restrict__ bias,
    float* __restrict__ out, int bx, int by)
{
  __shared__ short8 lds[2][4][512];   // 64 KB
  const int tid = threadIdx.x;
  const int lane = tid & 63, w = tid >> 6;
  const int bm0 = bx * 64, bn0 = by * 64;

  const int r0 = tid >> 3, c0 = tid & 7, g0 = c0 ^ (r0 & 7);
  const int r1 = r0 + 32,  g1 = c0 ^ (r1 & 7);
  const size_t aoff0 = (size_t)(bm0 + r0) * DMODEL + g0 * 8;
  const size_t aoff1 = (size_t)(bm0 + r1) * DMODEL + g1 * 8;
  const size_t boff0 = (size_t)(bn0 + r0) * DMODEL + g0 * 8;
  const size_t boff1 = (size_t)(bn0 + r1) * DMODEL + g1 * 8;

  const int mrb = (w >> 1) << 5, ncb = (w & 1) << 5;
  const int l15 = lane & 15, lh = lane >> 4, l7 = lane & 7;

  short8 st[8];
#define LOADS(K)                                        \
  { st[0] = *(const short8*)(xh + aoff0 + (K));         \
    st[1] = *(const short8*)(xh + aoff1 + (K));         \
    st[2] = *(const short8*)(xl + aoff0 + (K));         \
    st[3] = *(const short8*)(xl + aoff1 + (K));         \
    st[4] = *(const short8*)(wh + boff0 + (K));         \
    st[5] = *(const short8*)(wh + boff1 + (K));         \
    st[6] = *(const short8*)(wl + boff0 + (K));         \
    st[7] = *(const short8*)(wl + boff1 + (K)); }
#define WRITES(BUF)                                              \
  { lds[BUF][0][tid] = st[0]; lds[BUF][0][tid + 256] = st[1];    \
    lds[BUF][1][tid] = st[2]; lds[BUF][1][tid + 256] = st[3];    \
    lds[BUF][2][tid] = st[4]; lds[BUF][2][tid + 256] = st[5];    \
    lds[BUF][3][tid] = st[6]; lds[BUF][3][tid + 256] = st[7]; }

  f32x4 acc[2][2] = {};
  LOADS(0);
  WRITES(0);
  __syncthreads();

  int cur = 0;
  for (int t = 0; t < 8; ++t) {
    if (t < 7) LOADS((t + 1) * 64);
#pragma unroll
    for (int s = 0; s < 2; ++s) {
      const int chb = (s << 2) + lh;
      const int ra0 = (mrb + l15) * 8 + (chb ^ l7);
      const int ra1 = (mrb + 16 + l15) * 8 + (chb ^ l7);
      const int rb0 = (ncb + l15) * 8 + (chb ^ l7);
      const int rb1 = (ncb + 16 + l15) * 8 + (chb ^ l7);
      short8 a0h = lds[cur][0][ra0], a0l = lds[cur][1][ra0];
      short8 a1h = lds[cur][0][ra1], a1l = lds[cur][1][ra1];
      short8 w0h = lds[cur][2][rb0], w0l = lds[cur][3][rb0];
      short8 w1h = lds[cur][2][rb1], w1l = lds[cur][3][rb1];
#define MFMA_(A, B, C) C = __builtin_amdgcn_mfma_f32_16x16x32_bf16(A, B, C, 0, 0, 0)
      MFMA_(a0h, w0h, acc[0][0]); MFMA_(a0h, w0l, acc[0][0]); MFMA_(a0l, w0h, acc[0][0]);
      MFMA_(a0h, w1h, acc[0][1]); MFMA_(a0h, w1l, acc[0][1]); MFMA_(a0l, w1h, acc[0][1]);
      MFMA_(a1h, w0h, acc[1][0]); MFMA_(a1h, w0l, acc[1][0]); MFMA_(a1l, w0h, acc[1][0]);
      MFMA_(a1h, w1h, acc[1][1]); MFMA_(a1h, w1l, acc[1][1]); MFMA_(a1l, w1h, acc[1][1]);
#undef MFMA_
    }
    if (t < 7) WRITES(cur ^ 1);
    __syncthreads();
    cur ^= 1;
  }
#undef LOADS
#undef WRITES

  const int bm = bm0 + mrb, bn = bn0 + ncb;
#pragma unroll
  for (int mi = 0; mi < 2; ++mi)
#pragma unroll
    for (int ni = 0; ni < 2; ++ni) {
      const int C = bn + ni * 16 + l15;
      const float bv = bias[C];
#pragma unroll
      for (int e = 0; e < 4; ++e) {
        const int R = bm + mi * 16 + (lh << 2) + e;
        out[R * DMODEL + C] = acc[mi][ni][e] + bv;
      }
    }
}

__global__ __launch_bounds__(256) void proj_mfma_kernel(
    const float* __restrict__ q, const float* __restrict__ k, const float* __restrict__ v,
    const unsigned short* __restrict__ whi, const unsigned short* __restrict__ wlo,
    const float* __restrict__ bq, const float* __restrict__ bk, const float* __restrict__ bv,
    float* __restrict__ qh, float* __restrict__ kh, float* __restrict__ vh)
{
  // XCD-bijective swizzle over 384 blocks (=48*8)
  int lin = blockIdx.x + 16 * blockIdx.y + 128 * blockIdx.z;
  lin = (lin & 7) * 48 + (lin >> 3);
  const int bx = lin & 15, by = (lin >> 4) & 7, g = lin >> 7;
  const unsigned short* wh = whi + (size_t)g * DMODEL * DMODEL;
  const unsigned short* wl = wlo + (size_t)g * DMODEL * DMODEL;
  if (g == 0)      gemm_fp32A(q, wh, wl, bq, TWO_LOG2E, qh, 1, bx, by);
  else if (g == 1) gemm_fp32A(k, wh, wl, bk, TWO_LOG2E, kh, 1, bx, by);
  else             gemm_fp32A(v, wh, wl, bv, 1.0f, vh, 1, bx, by);
}

__global__ __launch_bounds__(256) void outproj_mfma_kernel(
    const unsigned short* __restrict__ aoh, const unsigned short* __restrict__ aol,
    const unsigned short* __restrict__ whi, const unsigned short* __restrict__ wlo,
    const float* __restrict__ b0, float* __restrict__ out)
{
  int lin = blockIdx.x + 16 * blockIdx.y;     // 128 blocks = 16*8
  lin = (lin & 7) * 16 + (lin >> 3);
  const int bx = lin & 15, by = lin >> 4;
  gemm_splitA(aoh, aol, whi + (size_t)3 * DMODEL * DMODEL,
              wlo + (size_t)3 * DMODEL * DMODEL, b0, out, bx, by);
}

// ---------------------------------------------------------------------------
// Fused Bahdanau attention (r9 version). qh,kh prescaled by 2*log2e.
// t_j = sum_d vp_d * rcp(exp2(q'+k') + 1); softmax in t-space:
// p = exp2(-2log2e*(t - min t)); masked -> t = +1e9.
// 1024 threads / 16 waves, 2 q-rows per wave; 152 KB LDS, 4 waves/SIMD.
// K staged [j][d] with XOR-swizzled float4 chunks -> ds_read_b128 score loads.
// ---------------------------------------------------------------------------
__global__ __launch_bounds__(1024, 4) void attn_kernel(
    const float* __restrict__ qh,   // (B,H,L,DK) prescaled
    const float* __restrict__ kh,   // (B,H,L,DK) prescaled
    const float* __restrict__ vh,   // (B,H,L,DK)
    const int* __restrict__ mask,   // (B,L,L)
    const float* __restrict__ vp,   // (H,DK)
    unsigned short* __restrict__ aoh,  // (B*L, D) bf16 hi
    unsigned short* __restrict__ aol)  // (B*L, D) bf16 lo
{
  __shared__ float kshf[DKH * LSEQ];    // 64 KB, [j][chunk^(j&15)] float4s
  __shared__ float vsh[LSEQ][DKH];      // 64 KB
  __shared__ float qsh[32][DKH];        // 8 KB
  __shared__ float psh[16][LSEQ];       // 16 KB
  __shared__ float vpsh[DKH];

  const int bh = blockIdx.x;            // b*8+h
  const int b = bh >> 3, h = bh & 7;
  const int i0 = blockIdx.y * 32;
  const int tid = threadIdx.x;
  const int lane = tid & 63, wv = tid >> 6;   // 16 waves

  const float* kbase = kh + (size_t)bh * LSEQ * DKH;
  for (int t = tid; t < LSEQ * DKH / 4; t += 1024) {
    const int j = t >> 4, c4 = t & 15;
    *(float4*)&kshf[(j << 6) + ((c4 ^ (j & 15)) << 2)] =
        *(const float4*)&kbase[(j << 6) + (c4 << 2)];
  }
  const float* vbase = vh + (size_t)bh * LSEQ * DKH;
  for (int t = tid; t < LSEQ * DKH / 4; t += 1024) {
    const int j = t >> 4, d4 = (t & 15) << 2;
    *(float4*)&vsh[j][d4] = *(const float4*)&vbase[j * DKH + d4];
  }
  if (tid < 512) {
    const float* qbase = qh + ((size_t)bh * LSEQ + i0) * DKH;
    const int r = tid >> 4, d4 = (tid & 15) << 2;
    *(float4*)&qsh[r][d4] = *(const float4*)&qbase[r * DKH + d4];
  }
  if (tid < DKH) vpsh[tid] = vp[h * DKH + tid];
  __syncthreads();

  // ---- score phase: 2 rows per wave, b128 K reads ----
  float tj[2][4] = {};
#pragma unroll 2
  for (int g = 0; g < 16; ++g) {
    float vpv[4], q0[4], q1[4];
    *(float4*)vpv = *(const float4*)&vpsh[g << 2];
    *(float4*)q0 = *(const float4*)&qsh[(wv << 1) + 0][g << 2];
    *(float4*)q1 = *(const float4*)&qsh[(wv << 1) + 1][g << 2];
#pragma unroll
    for (int c = 0; c < 4; ++c) {
      const int j = (c << 6) + lane;
      float kv[4];
      *(float4*)kv = *(const float4*)&kshf[(j << 6) + ((g ^ (j & 15)) << 2)];
#pragma unroll
      for (int t = 0; t < 4; ++t) {
        const float x0 = q0[t] + kv[t];
        const float e0 = __builtin_amdgcn_exp2f(x0);
        tj[0][c] = fmaf(vpv[t], __builtin_amdgcn_rcpf(e0 + 1.f), tj[0][c]);
        const float x1 = q1[t] + kv[t];
        const float e1 = __builtin_amdgcn_exp2f(x1);
        tj[1][c] = fmaf(vpv[t], __builtin_amdgcn_rcpf(e1 + 1.f), tj[1][c]);
      }
    }
  }

  // ---- per-row: mask, softmax (t-space), PV ----
  const int cg = lane >> 4, qq = lane & 15;
#pragma unroll
  for (int r = 0; r < 2; ++r) {
    const int i = i0 + (wv << 1) + r;
    const int* mrow = mask + ((size_t)b * LSEQ + i) * LSEQ;
    float t4[4];
#pragma unroll
    for (int c = 0; c < 4; ++c) {
      const int mv = mrow[(c << 6) + lane];
      t4[c] = mv ? tj[r][c] : 1.0e9f;
    }
    float m = fminf(fminf(t4[0], t4[1]), fminf(t4[2], t4[3]));
#pragma unroll
    for (int off = 32; off; off >>= 1) m = fminf(m, __shfl_xor(m, off));
    const float m2 = m * TWO_LOG2E;
    float p[4];
    float sum = 0.f;
#pragma unroll
    for (int c = 0; c < 4; ++c) {
      p[c] = __builtin_amdgcn_exp2f(fmaf(t4[c], -TWO_LOG2E, m2));
      sum += p[c];
    }
#pragma unroll
    for (int off = 32; off; off >>= 1) sum += __shfl_xor(sum, off);
    const float rs = __builtin_amdgcn_rcpf(sum);
#pragma unroll
    for (int c = 0; c < 4; ++c) psh[wv][(c << 6) + lane] = p[c];

    float o[4] = {0.f, 0.f, 0.f, 0.f};
#pragma unroll 4
    for (int jg = 0; jg < 16; ++jg) {
      float pv[4];
      *(float4*)pv = *(const float4*)&psh[wv][(cg << 6) + (jg << 2)];
#pragma unroll
      for (int t = 0; t < 4; ++t) {
        float v_[4];
        *(float4*)v_ = *(const float4*)&vsh[(cg << 6) + (jg << 2) + t][qq << 2];
#pragma unroll
        for (int u = 0; u < 4; ++u) o[u] = fmaf(pv[t], v_[u], o[u]);
      }
    }
#pragma unroll
    for (int off = 16; off <= 32; off <<= 1) {
#pragma unroll
      for (int u = 0; u < 4; ++u) o[u] += __shfl_xor(o[u], off);
    }
    if (lane < 16) {
      float ov[4];
#pragma unroll
      for (int u = 0; u < 4; ++u) ov[u] = o[u] * rs;
      ushort4 h4, l4;
      split4(ov, h4, l4);
      const int base = ((size_t)b * LSEQ + i) * DMODEL + h * DKH + (qq << 2);
      *(ushort4*)&aoh[base] = h4;
      *(ushort4*)&aol[base] = l4;
    }
  }
}

// ---------------------------------------------------------------------------
extern "C" void kernel_launch(void* const* d_in, const int* in_sizes, int n_in,
                              void* d_out, int out_size, void* d_ws, size_t ws_size,
                              hipStream_t stream) {
  const float* q   = (const float*)d_in[0];
  const float* k   = (const float*)d_in[1];
  const float* v   = (const float*)d_in[2];
  const int*  mask = (const int*)d_in[3];
  const float* Wq  = (const float*)d_in[4];
  const float* bq  = (const float*)d_in[5];
  const float* Wk  = (const float*)d_in[6];
  const float* bk  = (const float*)d_in[7];
  const float* Wv  = (const float*)d_in[8];
  const float* bv  = (const float*)d_in[9];
  const float* vp  = (const float*)d_in[10];
  const float* W0  = (const float*)d_in[11];
  const float* b0  = (const float*)d_in[12];
  float* outp = (float*)d_out;

  char* wsb = (char*)d_ws;
  unsigned short* whi = (unsigned short*)(wsb);                // 0-2 MB
  unsigned short* wlo = (unsigned short*)(wsb + (2u << 20));   // 2-4 MB
  float* qh = (float*)(wsb + (4u << 20));                      // 4-6 MB
  float* kh = (float*)(wsb + (6u << 20));                      // 6-8 MB
  float* vh = (float*)(wsb + (8u << 20));                      // 8-10 MB
  unsigned short* aoh = (unsigned short*)(wsb + (10u << 20));  // 10-11 MB
  unsigned short* aol = (unsigned short*)(wsb + (11u << 20));  // 11-12 MB

  prep_w_kernel<<<dim3(16, 16, 4), 256, 0, stream>>>(Wq, Wk, Wv, W0, whi, wlo);
  proj_mfma_kernel<<<dim3(16, 8, 3), 256, 0, stream>>>(q, k, v, whi, wlo,
                                                       bq, bk, bv, qh, kh, vh);
  attn_kernel<<<dim3(32, 8), 1024, 0, stream>>>(qh, kh, vh, mask, vp, aoh, aol);
  outproj_mfma_kernel<<<dim3(16, 8), 256, 0, stream>>>(aoh, aol, whi, wlo, b0, outp);
}

// Round 11
// 128.154 us; speedup vs baseline: 2.0829x; 1.0785x over previous
//
#include <hip/hip_runtime.h>

#define LSEQ 256
#define DMODEL 512
#define NHEAD 8
#define DKH 64
#define BATCH 4

#define TWO_LOG2E 2.885390081777927f

using short8 = __attribute__((ext_vector_type(8))) short;
using f32x4  = __attribute__((ext_vector_type(4))) float;

// split fp32 -> truncated bf16 hi + bf16(lo remainder)
__device__ __forceinline__ void split4(const float* f, ushort4& h, ushort4& l) {
  unsigned short hh[4], ll[4];
#pragma unroll
  for (int j = 0; j < 4; ++j) {
    unsigned int u = __float_as_uint(f[j]);
    hh[j] = (unsigned short)(u >> 16);
    float hf = __uint_as_float(u & 0xFFFF0000u);
    ll[j] = (unsigned short)(__float_as_uint(f[j] - hf) >> 16);
  }
  h = make_ushort4(hh[0], hh[1], hh[2], hh[3]);
  l = make_ushort4(ll[0], ll[1], ll[2], ll[3]);
}

__device__ __forceinline__ void split8(float4 f0, float4 f1, short8& h, short8& l) {
  float f[8] = {f0.x, f0.y, f0.z, f0.w, f1.x, f1.y, f1.z, f1.w};
#pragma unroll
  for (int j = 0; j < 8; ++j) {
    unsigned int u = __float_as_uint(f[j]);
    h[j] = (short)(u >> 16);
    float hf = __uint_as_float(u & 0xFFFF0000u);
    l[j] = (short)(__float_as_uint(f[j] - hf) >> 16);
  }
}

// ---------------------------------------------------------------------------
// prep_w: convert+transpose W (Wq,Wk,Wv,W0) to [g][n][k] bf16 hi/lo.
// Wq,Wk prescaled by 2*log2e. grid (16,16,4): k0=bx*32, n0=by*32, g=z.
// ---------------------------------------------------------------------------
__global__ __launch_bounds__(256) void prep_w_kernel(
    const float* __restrict__ Wq, const float* __restrict__ Wk,
    const float* __restrict__ Wv, const float* __restrict__ W0,
    unsigned short* __restrict__ whi, unsigned short* __restrict__ wlo)
{
  const int tid = threadIdx.x;
  const int g = blockIdx.z;
  const float* W = (g == 0) ? Wq : (g == 1) ? Wk : (g == 2) ? Wv : W0;
  const float scale = (g < 2) ? TWO_LOG2E : 1.0f;
  const int k0 = blockIdx.x * 32, n0 = blockIdx.y * 32;
  __shared__ float tile[32][36];
  {
    const int r = tid >> 3, c = (tid & 7) << 2;
    float4 f = *(const float4*)&W[(k0 + r) * DMODEL + n0 + c];
    tile[r][c + 0] = f.x * scale;
    tile[r][c + 1] = f.y * scale;
    tile[r][c + 2] = f.z * scale;
    tile[r][c + 3] = f.w * scale;
  }
  __syncthreads();
  const int n = tid >> 3, kk = (tid & 7) << 2;
  float x[4];
#pragma unroll
  for (int j = 0; j < 4; ++j) x[j] = tile[kk + j][n];
  ushort4 h4, l4;
  split4(x, h4, l4);
  const int base = (g * DMODEL + n0 + n) * DMODEL + k0 + kk;
  *(ushort4*)&whi[base] = h4;
  *(ushort4*)&wlo[base] = l4;
}

// ---------------------------------------------------------------------------
// Double-buffered bf16-split MFMA GEMM, fp32 A source (split during staging).
// Block tile 64x64, BK=64, 4 waves (32x32 quadrant each). One barrier/step.
// LDS [buf][Ah,Al,Bh,Bl][row*8+chunk], chunk XOR (row&7) both-sides.
// 3-product split: hi*hi + hi*lo + lo*hi.
// mode 0: out[R*512+C]; mode 1: head layout [((b*8+h)*256+l)*64+dk]
// ---------------------------------------------------------------------------
__device__ __forceinline__ void gemm_fp32A(
    const float* __restrict__ X,
    const unsigned short* __restrict__ wh, const unsigned short* __restrict__ wl,
    const float* __restrict__ bias, float bscale,
    float* __restrict__ out, int mode, int bx, int by)
{
  __shared__ short8 lds[2][4][512];   // 64 KB
  const int tid = threadIdx.x;
  const int lane = tid & 63, w = tid >> 6;
  const int bm0 = bx * 64, bn0 = by * 64;

  const int r0 = tid >> 3, c0 = tid & 7, g0 = c0 ^ (r0 & 7);
  const int r1 = r0 + 32,  g1 = c0 ^ (r1 & 7);
  const size_t aoff0 = (size_t)(bm0 + r0) * DMODEL + g0 * 8;
  const size_t aoff1 = (size_t)(bm0 + r1) * DMODEL + g1 * 8;
  const size_t boff0 = (size_t)(bn0 + r0) * DMODEL + g0 * 8;
  const size_t boff1 = (size_t)(bn0 + r1) * DMODEL + g1 * 8;

  const int mrb = (w >> 1) << 5, ncb = (w & 1) << 5;
  const int l15 = lane & 15, lh = lane >> 4, l7 = lane & 7;

  float4 af00, af01, af10, af11;
  short8 b0h, b0l, b1h, b1l;

#define LOADS(K)                                                  \
  { af00 = *(const float4*)(X + aoff0 + (K));                     \
    af01 = *(const float4*)(X + aoff0 + (K) + 4);                 \
    af10 = *(const float4*)(X + aoff1 + (K));                     \
    af11 = *(const float4*)(X + aoff1 + (K) + 4);                 \
    b0h = *(const short8*)(wh + boff0 + (K));                     \
    b0l = *(const short8*)(wl + boff0 + (K));                     \
    b1h = *(const short8*)(wh + boff1 + (K));                     \
    b1l = *(const short8*)(wl + boff1 + (K)); }
#define WRITES(BUF)                                               \
  { short8 h_, l_;                                                \
    split8(af00, af01, h_, l_);                                   \
    lds[BUF][0][tid] = h_; lds[BUF][1][tid] = l_;                 \
    split8(af10, af11, h_, l_);                                   \
    lds[BUF][0][tid + 256] = h_; lds[BUF][1][tid + 256] = l_;     \
    lds[BUF][2][tid] = b0h; lds[BUF][3][tid] = b0l;               \
    lds[BUF][2][tid + 256] = b1h; lds[BUF][3][tid + 256] = b1l; }

  f32x4 acc[2][2] = {};
  LOADS(0);
  WRITES(0);
  __syncthreads();

  int cur = 0;
  for (int t = 0; t < 8; ++t) {
    if (t < 7) LOADS((t + 1) * 64);
#pragma unroll
    for (int s = 0; s < 2; ++s) {
      const int chb = (s << 2) + lh;
      const int ra0 = (mrb + l15) * 8 + (chb ^ l7);
      const int ra1 = (mrb + 16 + l15) * 8 + (chb ^ l7);
      const int rb0 = (ncb + l15) * 8 + (chb ^ l7);
      const int rb1 = (ncb + 16 + l15) * 8 + (chb ^ l7);
      short8 a0h = lds[cur][0][ra0], a0l = lds[cur][1][ra0];
      short8 a1h = lds[cur][0][ra1], a1l = lds[cur][1][ra1];
      short8 w0h = lds[cur][2][rb0], w0l = lds[cur][3][rb0];
      short8 w1h = lds[cur][2][rb1], w1l = lds[cur][3][rb1];
#define MFMA_(A, B, C) C = __builtin_amdgcn_mfma_f32_16x16x32_bf16(A, B, C, 0, 0, 0)
      MFMA_(a0h, w0h, acc[0][0]); MFMA_(a0h, w0l, acc[0][0]); MFMA_(a0l, w0h, acc[0][0]);
      MFMA_(a0h, w1h, acc[0][1]); MFMA_(a0h, w1l, acc[0][1]); MFMA_(a0l, w1h, acc[0][1]);
      MFMA_(a1h, w0h, acc[1][0]); MFMA_(a1h, w0l, acc[1][0]); MFMA_(a1l, w0h, acc[1][0]);
      MFMA_(a1h, w1h, acc[1][1]); MFMA_(a1h, w1l, acc[1][1]); MFMA_(a1l, w1h, acc[1][1]);
#undef MFMA_
    }
    if (t < 7) WRITES(cur ^ 1);
    __syncthreads();
    cur ^= 1;
  }
#undef LOADS
#undef WRITES

  const int bm = bm0 + mrb, bn = bn0 + ncb;
#pragma unroll
  for (int mi = 0; mi < 2; ++mi)
#pragma unroll
    for (int ni = 0; ni < 2; ++ni) {
      const int C = bn + ni * 16 + l15;
      const float bv = bscale * bias[C];
#pragma unroll
      for (int e = 0; e < 4; ++e) {
        const int R = bm + mi * 16 + (lh << 2) + e;
        const float val = acc[mi][ni][e] + bv;
        if (mode == 0) {
          out[R * DMODEL + C] = val;
        } else {
          const int b = R >> 8, l = R & (LSEQ - 1);
          const int hh = C >> 6, dk = C & 63;
          out[((b * NHEAD + hh) * LSEQ + l) * DKH + dk] = val;
        }
      }
    }
}

// same skeleton, pre-split bf16 A source (short8 loads, no in-kernel split)
__device__ __forceinline__ void gemm_splitA(
    const unsigned short* __restrict__ xh, const unsigned short* __restrict__ xl,
    const unsigned short* __restrict__ wh, const unsigned short* __restrict__ wl,
    const float* __restrict__ bias,
    float* __restrict__ out, int bx, int by)
{
  __shared__ short8 lds[2][4][512];   // 64 KB
  const int tid = threadIdx.x;
  const int lane = tid & 63, w = tid >> 6;
  const int bm0 = bx * 64, bn0 = by * 64;

  const int r0 = tid >> 3, c0 = tid & 7, g0 = c0 ^ (r0 & 7);
  const int r1 = r0 + 32,  g1 = c0 ^ (r1 & 7);
  const size_t aoff0 = (size_t)(bm0 + r0) * DMODEL + g0 * 8;
  const size_t aoff1 = (size_t)(bm0 + r1) * DMODEL + g1 * 8;
  const size_t boff0 = (size_t)(bn0 + r0) * DMODEL + g0 * 8;
  const size_t boff1 = (size_t)(bn0 + r1) * DMODEL + g1 * 8;

  const int mrb = (w >> 1) << 5, ncb = (w & 1) << 5;
  const int l15 = lane & 15, lh = lane >> 4, l7 = lane & 7;

  short8 st[8];
#define LOADS(K)                                        \
  { st[0] = *(const short8*)(xh + aoff0 + (K));         \
    st[1] = *(const short8*)(xh + aoff1 + (K));         \
    st[2] = *(const short8*)(xl + aoff0 + (K));         \
    st[3] = *(const short8*)(xl + aoff1 + (K));         \
    st[4] = *(const short8*)(wh + boff0 + (K));         \
    st[5] = *(const short8*)(wh + boff1 + (K));         \
    st[6] = *(const short8*)(wl + boff0 + (K));         \
    st[7] = *(const short8*)(wl + boff1 + (K)); }
#define WRITES(BUF)                                              \
  { lds[BUF][0][tid] = st[0]; lds[BUF][0][tid + 256] = st[1];    \
    lds[BUF][1][tid] = st[2]; lds[BUF][1][tid + 256] = st[3];    \
    lds[BUF][2][tid] = st[4]; lds[BUF][2][tid + 256] = st[5];    \
    lds[BUF][3][tid] = st[6]; lds[BUF][3][tid + 256] = st[7]; }

  f32x4 acc[2][2] = {};
  LOADS(0);
  WRITES(0);
  __syncthreads();

  int cur = 0;
  for (int t = 0; t < 8; ++t) {
    if (t < 7) LOADS((t + 1) * 64);
#pragma unroll
    for (int s = 0; s < 2; ++s) {
      const int chb = (s << 2) + lh;
      const int ra0 = (mrb + l15) * 8 + (chb ^ l7);
      const int ra1 = (mrb + 16 + l15) * 8 + (chb ^ l7);
      const int rb0 = (ncb + l15) * 8 + (chb ^ l7);
      const int rb1 = (ncb + 16 + l15) * 8 + (chb ^ l7);
      short8 a0h = lds[cur][0][ra0], a0l = lds[cur][1][ra0];
      short8 a1h = lds[cur][0][ra1], a1l = lds[cur][1][ra1];
      short8 w0h = lds[cur][2][rb0], w0l = lds[cur][3][rb0];
      short8 w1h = lds[cur][2][rb1], w1l = lds[cur][3][rb1];
#define MFMA_(A, B, C) C = __builtin_amdgcn_mfma_f32_16x16x32_bf16(A, B, C, 0, 0, 0)
      MFMA_(a0h, w0h, acc[0][0]); MFMA_(a0h, w0l, acc[0][0]); MFMA_(a0l, w0h, acc[0][0]);
      MFMA_(a0h, w1h, acc[0][1]); MFMA_(a0h, w1l, acc[0][1]); MFMA_(a0l, w1h, acc[0][1]);
      MFMA_(a1h, w0h, acc[1][0]); MFMA_(a1h, w0l, acc[1][0]); MFMA_(a1l, w0h, acc[1][0]);
      MFMA_(a1h, w1h, acc[1][1]); MFMA_(a1h, w1l, acc[1][1]); MFMA_(a1l, w1h, acc[1][1]);
#undef MFMA_
    }
    if (t < 7) WRITES(cur ^ 1);
    __syncthreads();
    cur ^= 1;
  }
#undef LOADS
#undef WRITES

  const int bm = bm0 + mrb, bn = bn0 + ncb;
#pragma unroll
  for (int mi = 0; mi < 2; ++mi)
#pragma unroll
    for (int ni = 0; ni < 2; ++ni) {
      const int C = bn + ni * 16 + l15;
      const float bv = bias[C];
#pragma unroll
      for (int e = 0; e < 4; ++e) {
        const int R = bm + mi * 16 + (lh << 2) + e;
        out[R * DMODEL + C] = acc[mi][ni][e] + bv;
      }
    }
}

__global__ __launch_bounds__(256) void proj_mfma_kernel(
    const float* __restrict__ q, const float* __restrict__ k, const float* __restrict__ v,
    const unsigned short* __restrict__ whi, const unsigned short* __restrict__ wlo,
    const float* __restrict__ bq, const float* __restrict__ bk, const float* __restrict__ bv,
    float* __restrict__ qh, float* __restrict__ kh, float* __restrict__ vh)
{
  // XCD-bijective swizzle over 384 blocks (=48*8)
  int lin = blockIdx.x + 16 * blockIdx.y + 128 * blockIdx.z;
  lin = (lin & 7) * 48 + (lin >> 3);
  const int bx = lin & 15, by = (lin >> 4) & 7, g = lin >> 7;
  const unsigned short* wh = whi + (size_t)g * DMODEL * DMODEL;
  const unsigned short* wl = wlo + (size_t)g * DMODEL * DMODEL;
  if (g == 0)      gemm_fp32A(q, wh, wl, bq, TWO_LOG2E, qh, 1, bx, by);
  else if (g == 1) gemm_fp32A(k, wh, wl, bk, TWO_LOG2E, kh, 1, bx, by);
  else             gemm_fp32A(v, wh, wl, bv, 1.0f, vh, 1, bx, by);
}

__global__ __launch_bounds__(256) void outproj_mfma_kernel(
    const unsigned short* __restrict__ aoh, const unsigned short* __restrict__ aol,
    const unsigned short* __restrict__ whi, const unsigned short* __restrict__ wlo,
    const float* __restrict__ b0, float* __restrict__ out)
{
  int lin = blockIdx.x + 16 * blockIdx.y;     // 128 blocks = 16*8
  lin = (lin & 7) * 16 + (lin >> 3);
  const int bx = lin & 15, by = lin >> 4;
  gemm_splitA(aoh, aol, whi + (size_t)3 * DMODEL * DMODEL,
              wlo + (size_t)3 * DMODEL * DMODEL, b0, out, bx, by);
}

// ---------------------------------------------------------------------------
// Fused Bahdanau attention. qh,kh prescaled by 2*log2e.
// Factored exponential: exp2(q'+k') = Eq*Ek with Ek=exp2(k') precomputed once
// per (j,d) at staging (shared by all 32 rows) and Eq=exp2(q') per row.
// t_j = sum_d vp_d * rcp(Eq*Ek + 1); softmax in t-space:
// p = exp2(-2log2e*(t - min t)); masked -> t = +1e9.
// 1024 threads / 16 waves, 2 q-rows per wave; 152 KB LDS, 4 waves/SIMD.
// Ek staged [j][d] with XOR-swizzled float4 chunks -> ds_read_b128 loads.
// ---------------------------------------------------------------------------
__global__ __launch_bounds__(1024, 4) void attn_kernel(
    const float* __restrict__ qh,   // (B,H,L,DK) prescaled
    const float* __restrict__ kh,   // (B,H,L,DK) prescaled
    const float* __restrict__ vh,   // (B,H,L,DK)
    const int* __restrict__ mask,   // (B,L,L)
    const float* __restrict__ vp,   // (H,DK)
    unsigned short* __restrict__ aoh,  // (B*L, D) bf16 hi
    unsigned short* __restrict__ aol)  // (B*L, D) bf16 lo
{
  __shared__ float kshf[DKH * LSEQ];    // 64 KB, Ek [j][chunk^(j&15)] float4s
  __shared__ float vsh[LSEQ][DKH];      // 64 KB
  __shared__ float qsh[32][DKH];        // 8 KB (Eq)
  __shared__ float psh[16][LSEQ];       // 16 KB
  __shared__ float vpsh[DKH];

  const int bh = blockIdx.x;            // b*8+h
  const int b = bh >> 3, h = bh & 7;
  const int i0 = blockIdx.y * 32;
  const int tid = threadIdx.x;
  const int lane = tid & 63, wv = tid >> 6;   // 16 waves

  const float* kbase = kh + (size_t)bh * LSEQ * DKH;
  for (int t = tid; t < LSEQ * DKH / 4; t += 1024) {
    const int j = t >> 4, c4 = t & 15;
    float4 kf = *(const float4*)&kbase[(j << 6) + (c4 << 2)];
    kf.x = __builtin_amdgcn_exp2f(kf.x);
    kf.y = __builtin_amdgcn_exp2f(kf.y);
    kf.z = __builtin_amdgcn_exp2f(kf.z);
    kf.w = __builtin_amdgcn_exp2f(kf.w);
    *(float4*)&kshf[(j << 6) + ((c4 ^ (j & 15)) << 2)] = kf;
  }
  const float* vbase = vh + (size_t)bh * LSEQ * DKH;
  for (int t = tid; t < LSEQ * DKH / 4; t += 1024) {
    const int j = t >> 4, d4 = (t & 15) << 2;
    *(float4*)&vsh[j][d4] = *(const float4*)&vbase[j * DKH + d4];
  }
  if (tid < 512) {
    const float* qbase = qh + ((size_t)bh * LSEQ + i0) * DKH;
    const int r = tid >> 4, d4 = (tid & 15) << 2;
    float4 qf = *(const float4*)&qbase[r * DKH + d4];
    qf.x = __builtin_amdgcn_exp2f(qf.x);
    qf.y = __builtin_amdgcn_exp2f(qf.y);
    qf.z = __builtin_amdgcn_exp2f(qf.z);
    qf.w = __builtin_amdgcn_exp2f(qf.w);
    *(float4*)&qsh[r][d4] = qf;
  }
  if (tid < DKH) vpsh[tid] = vp[h * DKH + tid];
  __syncthreads();

  // ---- score phase: 2 rows per wave, b128 Ek reads, 1 trans/element ----
  float tj[2][4] = {};
#pragma unroll 2
  for (int g = 0; g < 16; ++g) {
    float vpv[4], q0[4], q1[4];
    *(float4*)vpv = *(const float4*)&vpsh[g << 2];
    *(float4*)q0 = *(const float4*)&qsh[(wv << 1) + 0][g << 2];
    *(float4*)q1 = *(const float4*)&qsh[(wv << 1) + 1][g << 2];
#pragma unroll
    for (int c = 0; c < 4; ++c) {
      const int j = (c << 6) + lane;
      float kv[4];
      *(float4*)kv = *(const float4*)&kshf[(j << 6) + ((g ^ (j & 15)) << 2)];
#pragma unroll
      for (int t = 0; t < 4; ++t) {
        const float e0 = q0[t] * kv[t];
        tj[0][c] = fmaf(vpv[t], __builtin_amdgcn_rcpf(e0 + 1.f), tj[0][c]);
        const float e1 = q1[t] * kv[t];
        tj[1][c] = fmaf(vpv[t], __builtin_amdgcn_rcpf(e1 + 1.f), tj[1][c]);
      }
    }
  }

  // ---- per-row: mask, softmax (t-space), PV ----
  const int cg = lane >> 4, qq = lane & 15;
#pragma unroll
  for (int r = 0; r < 2; ++r) {
    const int i = i0 + (wv << 1) + r;
    const int* mrow = mask + ((size_t)b * LSEQ + i) * LSEQ;
    float t4[4];
#pragma unroll
    for (int c = 0; c < 4; ++c) {
      const int mv = mrow[(c << 6) + lane];
      t4[c] = mv ? tj[r][c] : 1.0e9f;
    }
    float m = fminf(fminf(t4[0], t4[1]), fminf(t4[2], t4[3]));
#pragma unroll
    for (int off = 32; off; off >>= 1) m = fminf(m, __shfl_xor(m, off));
    const float m2 = m * TWO_LOG2E;
    float p[4];
    float sum = 0.f;
#pragma unroll
    for (int c = 0; c < 4; ++c) {
      p[c] = __builtin_amdgcn_exp2f(fmaf(t4[c], -TWO_LOG2E, m2));
      sum += p[c];
    }
#pragma unroll
    for (int off = 32; off; off >>= 1) sum += __shfl_xor(sum, off);
    const float rs = __builtin_amdgcn_rcpf(sum);
#pragma unroll
    for (int c = 0; c < 4; ++c) psh[wv][(c << 6) + lane] = p[c];

    float o[4] = {0.f, 0.f, 0.f, 0.f};
#pragma unroll 4
    for (int jg = 0; jg < 16; ++jg) {
      float pv[4];
      *(float4*)pv = *(const float4*)&psh[wv][(cg << 6) + (jg << 2)];
#pragma unroll
      for (int t = 0; t < 4; ++t) {
        float v_[4];
        *(float4*)v_ = *(const float4*)&vsh[(cg << 6) + (jg << 2) + t][qq << 2];
#pragma unroll
        for (int u = 0; u < 4; ++u) o[u] = fmaf(pv[t], v_[u], o[u]);
      }
    }
#pragma unroll
    for (int off = 16; off <= 32; off <<= 1) {
#pragma unroll
      for (int u = 0; u < 4; ++u) o[u] += __shfl_xor(o[u], off);
    }
    if (lane < 16) {
      float ov[4];
#pragma unroll
      for (int u = 0; u < 4; ++u) ov[u] = o[u] * rs;
      ushort4 h4, l4;
      split4(ov, h4, l4);
      const int base = ((size_t)b * LSEQ + i) * DMODEL + h * DKH + (qq << 2);
      *(ushort4*)&aoh[base] = h4;
      *(ushort4*)&aol[base] = l4;
    }
  }
}

// ---------------------------------------------------------------------------
extern "C" void kernel_launch(void* const* d_in, const int* in_sizes, int n_in,
                              void* d_out, int out_size, void* d_ws, size_t ws_size,
                              hipStream_t stream) {
  const float* q   = (const float*)d_in[0];
  const float* k   = (const float*)d_in[1];
  const float* v   = (const float*)d_in[2];
  const int*  mask = (const int*)d_in[3];
  const float* Wq  = (const float*)d_in[4];
  const float* bq  = (const float*)d_in[5];
  const float* Wk  = (const float*)d_in[6];
  const float* bk  = (const float*)d_in[7];
  const float* Wv  = (const float*)d_in[8];
  const float* bv  = (const float*)d_in[9];
  const float* vp  = (const float*)d_in[10];
  const float* W0  = (const float*)d_in[11];
  const float* b0  = (const float*)d_in[12];
  float* outp = (float*)d_out;

  char* wsb = (char*)d_ws;
  unsigned short* whi = (unsigned short*)(wsb);                // 0-2 MB
  unsigned short* wlo = (unsigned short*)(wsb + (2u << 20));   // 2-4 MB
  float* qh = (float*)(wsb + (4u << 20));                      // 4-6 MB
  float* kh = (float*)(wsb + (6u << 20));                      // 6-8 MB
  float* vh = (float*)(wsb + (8u << 20));                      // 8-10 MB
  unsigned short* aoh = (unsigned short*)(wsb + (10u << 20));  // 10-11 MB
  unsigned short* aol = (unsigned short*)(wsb + (11u << 20));  // 11-12 MB

  prep_w_kernel<<<dim3(16, 16, 4), 256, 0, stream>>>(Wq, Wk, Wv, W0, whi, wlo);
  proj_mfma_kernel<<<dim3(16, 8, 3), 256, 0, stream>>>(q, k, v, whi, wlo,
                                                       bq, bk, bv, qh, kh, vh);
  attn_kernel<<<dim3(32, 8), 1024, 0, stream>>>(qh, kh, vh, mask, vp, aoh, aol);
  outproj_mfma_kernel<<<dim3(16, 8), 256, 0, stream>>>(aoh, aol, whi, wlo, b0, outp);
}